// Round 1
// baseline (3712.827 us; speedup 1.0000x reference)
//
#include <hip/hip_runtime.h>
#include <hip/hip_bf16.h>

#define NSN 5000
#define NMN 100000
#define NRN 2000
#define HDIM 128
#define ESM 2000000
#define ERM 1000000
#define ESIM 2000000
#define LBL 500000

// ---------------- utility kernels ----------------

__global__ void zero_int(int* __restrict__ p, int n) {
  int i = blockIdx.x * blockDim.x + threadIdx.x;
  if (i < n) p[i] = 0;
}

__global__ void hist_kernel(const int* __restrict__ idx, int n, int* __restrict__ cnt) {
  int i = blockIdx.x * blockDim.x + threadIdx.x;
  if (i < n) atomicAdd(&cnt[idx[i]], 1);
}

// 3-phase exclusive scan: partial block sums -> scan block sums -> write offsets
__global__ void scan_partial(const int* __restrict__ cnt, int n, int* __restrict__ bsum) {
  __shared__ int sdata[256];
  int b = blockIdx.x, t = threadIdx.x;
  int base = b * 1024;
  int s = 0;
  for (int j = t; j < 1024; j += 256) { int i = base + j; if (i < n) s += cnt[i]; }
  sdata[t] = s; __syncthreads();
  for (int o = 128; o > 0; o >>= 1) { if (t < o) sdata[t] += sdata[t + o]; __syncthreads(); }
  if (t == 0) bsum[b] = sdata[0];
}

__global__ void scan_bsum(int* __restrict__ bsum, int nb, int* __restrict__ total_out) {
  __shared__ int buf[128];
  int t = threadIdx.x;
  int v = (t < nb) ? bsum[t] : 0;
  buf[t] = v; __syncthreads();
  for (int o = 1; o < 128; o <<= 1) {
    int a = (t >= o) ? buf[t - o] : 0;
    __syncthreads();
    buf[t] += a;
    __syncthreads();
  }
  if (t < nb) bsum[t] = buf[t] - v;   // exclusive
  if (t == 0) *total_out = buf[127];  // total (padding contributes 0)
}

__global__ void scan_write(const int* __restrict__ cnt, int n, const int* __restrict__ bsum,
                           int* __restrict__ off) {
  __shared__ int buf[256];
  int b = blockIdx.x, t = threadIdx.x;
  int base = b * 1024 + t * 4;
  int v0 = 0, v1 = 0, v2 = 0, v3 = 0;
  if (base + 0 < n) v0 = cnt[base + 0];
  if (base + 1 < n) v1 = cnt[base + 1];
  if (base + 2 < n) v2 = cnt[base + 2];
  if (base + 3 < n) v3 = cnt[base + 3];
  int s = v0 + v1 + v2 + v3;
  buf[t] = s; __syncthreads();
  for (int o = 1; o < 256; o <<= 1) {
    int a = (t >= o) ? buf[t - o] : 0;
    __syncthreads();
    buf[t] += a;
    __syncthreads();
  }
  int run = buf[t] - s + bsum[b];
  if (base + 0 < n) off[base + 0] = run; run += v0;
  if (base + 1 < n) off[base + 1] = run; run += v1;
  if (base + 2 < n) off[base + 2] = run; run += v2;
  if (base + 3 < n) off[base + 3] = run;
}

__global__ void fillcsr(const int* __restrict__ srcids, const int* __restrict__ dstids, int n,
                        const int* __restrict__ off, int* __restrict__ cur, int* __restrict__ list) {
  int i = blockIdx.x * blockDim.x + threadIdx.x;
  if (i < n) {
    int d = dstids[i];
    int p = atomicAdd(&cur[d], 1);
    list[off[d] + p] = srcids[i];
  }
}

__global__ void compute_dinv(const int* __restrict__ off1, const int* __restrict__ off2,
                             float* __restrict__ dinv1, float* __restrict__ dinv2, int n) {
  int v = blockIdx.x * blockDim.x + threadIdx.x;
  if (v < n) {
    dinv1[v] = rsqrtf((float)(off1[v + 1] - off1[v] + 1));  // deg incl. self-loop >= 1
    dinv2[v] = rsqrtf((float)(off2[v + 1] - off2[v] + 1));
  }
}

// Wr_m[l] = sage_Wr[l,0]+sage_Wr[l,2]; bias_m[l] = sage_bl[l,0]+sage_bl[l,2]+gcn_b[l,0]+gcn_b[l,1]
__global__ void prep_weights(const float* __restrict__ sWr, const float* __restrict__ sbl,
                             const float* __restrict__ gb, float* __restrict__ WrM,
                             float* __restrict__ biasM) {
  int i = blockIdx.x * blockDim.x + threadIdx.x;
  if (i < 2 * 16384) {
    int l = i >> 14, j = i & 16383;
    WrM[i] = sWr[(l * 4 + 0) * 16384 + j] + sWr[(l * 4 + 2) * 16384 + j];
  }
  if (i < 2 * 128) {
    int l = i >> 7, j = i & 127;
    biasM[i] = sbl[(l * 4 + 0) * 128 + j] + sbl[(l * 4 + 2) * 128 + j] +
               gb[(l * 2 + 0) * 128 + j] + gb[(l * 2 + 1) * 128 + j];
  }
}

// ---------------- aggregation (pull, one wave per dst node) ----------------

__global__ void sage_agg(const float* __restrict__ x, const int* __restrict__ list,
                         const int* __restrict__ off, float* __restrict__ outbuf, int n) {
  int w = (blockIdx.x * blockDim.x + threadIdx.x) >> 6;
  if (w >= n) return;
  int lane = threadIdx.x & 63;
  int s = off[w], e = off[w + 1];
  float ax = 0.f, ay = 0.f;
  int i = s;
  for (; i + 2 <= e; i += 2) {
    int u0 = list[i], u1 = list[i + 1];
    float2 v0 = ((const float2*)(x + (size_t)u0 * HDIM))[lane];
    float2 v1 = ((const float2*)(x + (size_t)u1 * HDIM))[lane];
    ax += v0.x + v1.x; ay += v0.y + v1.y;
  }
  if (i < e) {
    int u = list[i];
    float2 v = ((const float2*)(x + (size_t)u * HDIM))[lane];
    ax += v.x; ay += v.y;
  }
  float inv = (e > s) ? 1.0f / (float)(e - s) : 0.0f;  // mean / max(cnt,1); cnt=0 -> acc=0
  float2 o; o.x = ax * inv; o.y = ay * inv;
  ((float2*)(outbuf + (size_t)w * HDIM))[lane] = o;
}

__global__ void gcn_agg(const float* __restrict__ x, const int* __restrict__ list,
                        const int* __restrict__ off, const float* __restrict__ dinv,
                        float* __restrict__ outbuf, int n) {
  int w = (blockIdx.x * blockDim.x + threadIdx.x) >> 6;
  if (w >= n) return;
  int lane = threadIdx.x & 63;
  int s = off[w], e = off[w + 1];
  float ax = 0.f, ay = 0.f;
  int i = s;
  for (; i + 2 <= e; i += 2) {
    int u0 = list[i], u1 = list[i + 1];
    float d0 = dinv[u0], d1 = dinv[u1];
    float2 v0 = ((const float2*)(x + (size_t)u0 * HDIM))[lane];
    float2 v1 = ((const float2*)(x + (size_t)u1 * HDIM))[lane];
    ax += v0.x * d0 + v1.x * d1; ay += v0.y * d0 + v1.y * d1;
  }
  if (i < e) {
    int u = list[i];
    float du = dinv[u];
    float2 v = ((const float2*)(x + (size_t)u * HDIM))[lane];
    ax += v.x * du; ay += v.y * du;
  }
  float dw = dinv[w];
  float2 xv = ((const float2*)(x + (size_t)w * HDIM))[lane];
  float2 o;
  o.x = ax * dw + xv.x * dw * dw;  // edges + self-loop (norm = dinv[w]^2)
  o.y = ay * dw + xv.y * dw * dw;
  ((float2*)(outbuf + (size_t)w * HDIM))[lane] = o;
}

// ---------------- GEMM: out = maybe_relu( Cin? + bias? + A1@W1 + A2?@W2 ) ----------------
// A: [n,128] row-major, W: [128,128] row-major. 64 rows/block, 256 threads.

__global__ __launch_bounds__(256) void gemm128(
    const float* __restrict__ A1, const float* __restrict__ W1,
    const float* __restrict__ A2, const float* __restrict__ W2,
    const float* Cin, const float* __restrict__ bias,
    float* out, int n, int relu) {
  __shared__ float As[64 * HDIM];
  int tid = threadIdx.x;
  int tx = tid & 31;   // cols tx*4 .. tx*4+3
  int ty = tid >> 5;   // rows ty + 8*i, i in 0..7
  int r0 = blockIdx.x * 64;

  float acc[8][4];
  float4 bv = bias ? *(const float4*)(bias + tx * 4) : make_float4(0.f, 0.f, 0.f, 0.f);
#pragma unroll
  for (int i = 0; i < 8; i++) { acc[i][0] = bv.x; acc[i][1] = bv.y; acc[i][2] = bv.z; acc[i][3] = bv.w; }

  for (int pass = 0; pass < 2; ++pass) {
    const float* A = pass ? A2 : A1;
    const float* W = pass ? W2 : W1;
    if (!A) break;
    __syncthreads();  // protect As reuse across passes
    for (int j = tid; j < 64 * 32; j += 256) {
      int row = j >> 5, c4 = j & 31;
      float4 v = make_float4(0.f, 0.f, 0.f, 0.f);
      if (r0 + row < n) v = *(const float4*)(A + (size_t)(r0 + row) * HDIM + c4 * 4);
      *(float4*)&As[row * HDIM + c4 * 4] = v;
    }
    __syncthreads();
    for (int k = 0; k < HDIM; k += 4) {
      float4 wv[4];
#pragma unroll
      for (int kk = 0; kk < 4; kk++)
        wv[kk] = *(const float4*)(W + (size_t)(k + kk) * HDIM + tx * 4);
#pragma unroll
      for (int i = 0; i < 8; i++) {
        float4 a = *(const float4*)&As[(ty + i * 8) * HDIM + k];
        float av[4] = {a.x, a.y, a.z, a.w};
#pragma unroll
        for (int kk = 0; kk < 4; kk++) {
          acc[i][0] = fmaf(av[kk], wv[kk].x, acc[i][0]);
          acc[i][1] = fmaf(av[kk], wv[kk].y, acc[i][1]);
          acc[i][2] = fmaf(av[kk], wv[kk].z, acc[i][2]);
          acc[i][3] = fmaf(av[kk], wv[kk].w, acc[i][3]);
        }
      }
    }
  }

#pragma unroll
  for (int i = 0; i < 8; i++) {
    int r = r0 + ty + i * 8;
    if (r < n) {
      float4 o = make_float4(acc[i][0], acc[i][1], acc[i][2], acc[i][3]);
      if (Cin) {
        float4 c = *(const float4*)(Cin + (size_t)r * HDIM + tx * 4);
        o.x += c.x; o.y += c.y; o.z += c.z; o.w += c.w;
      }
      if (relu) { o.x = fmaxf(o.x, 0.f); o.y = fmaxf(o.y, 0.f); o.z = fmaxf(o.z, 0.f); o.w = fmaxf(o.w, 0.f); }
      *(float4*)(out + (size_t)r * HDIM + tx * 4) = o;
    }
  }
}

// ---------------- final dot products (one wave per label pair) ----------------

__global__ void dots_kernel(const float* __restrict__ xs, const float* __restrict__ xm,
                            const float* __restrict__ xr, const int* __restrict__ ls,
                            const int* __restrict__ lm, const int* __restrict__ lr,
                            float* __restrict__ out) {
  int i = (blockIdx.x * blockDim.x + threadIdx.x) >> 6;
  if (i >= LBL) return;
  int lane = threadIdx.x & 63;
  float2 m2 = ((const float2*)(xm + (size_t)lm[i] * HDIM))[lane];
  float2 s2 = ((const float2*)(xs + (size_t)ls[i] * HDIM))[lane];
  float2 r2 = ((const float2*)(xr + (size_t)lr[i] * HDIM))[lane];
  float p1 = s2.x * m2.x + s2.y * m2.y;
  float p2 = r2.x * m2.x + r2.y * m2.y;
#pragma unroll
  for (int o = 32; o > 0; o >>= 1) {
    p1 += __shfl_down(p1, o, 64);
    p2 += __shfl_down(p2, o, 64);
  }
  if (lane == 0) { out[i] = p1; out[LBL + i] = p2; }
}

// ---------------- host launcher ----------------

extern "C" void kernel_launch(void* const* d_in, const int* in_sizes, int n_in,
                              void* d_out, int out_size, void* d_ws, size_t ws_size,
                              hipStream_t stream) {
  const float* emb_s = (const float*)d_in[0];
  const float* emb_m = (const float*)d_in[1];
  const float* emb_r = (const float*)d_in[2];
  const float* sWl = (const float*)d_in[3];
  const float* sbl = (const float*)d_in[4];
  const float* sWr = (const float*)d_in[5];
  const float* gW  = (const float*)d_in[6];
  const float* gb  = (const float*)d_in[7];
  const int* src_sm  = (const int*)d_in[8];
  const int* dst_sm  = (const int*)d_in[9];
  const int* src_rm  = (const int*)d_in[10];
  const int* dst_rm  = (const int*)d_in[11];
  const int* src_sim = (const int*)d_in[12];
  const int* dst_sim = (const int*)d_in[13];
  const int* lbl_s = (const int*)d_in[14];
  const int* lbl_m = (const int*)d_in[15];
  const int* lbl_r = (const int*)d_in[16];
  float* out = (float*)d_out;

  char* p = (char*)d_ws;
  auto alloc = [&](size_t bytes) -> char* {
    char* r = p;
    p += (bytes + 255) & ~(size_t)255;
    return r;
  };

  const int CNT_TOTAL = 4 * NMN + NSN + NRN;  // 407000
  int* cnt_base = (int*)alloc(sizeof(int) * CNT_TOTAL);
  int* cnt_sm_d = cnt_base;            // NM
  int* cnt_sm_s = cnt_sm_d + NMN;      // NS
  int* cnt_rm_d = cnt_sm_s + NSN;      // NM
  int* cnt_rm_s = cnt_rm_d + NMN;      // NR
  int* cnt_si_d = cnt_rm_s + NRN;      // NM
  int* cnt_si_s = cnt_si_d + NMN;      // NM

  int* off_base = (int*)alloc(sizeof(int) * (CNT_TOTAL + 6));
  int* off_sm  = off_base;             // NM+1
  int* off_ms  = off_sm + NMN + 1;     // NS+1
  int* off_rm  = off_ms + NSN + 1;     // NM+1
  int* off_mr  = off_rm + NMN + 1;     // NR+1
  int* off_si  = off_mr + NRN + 1;     // NM+1
  int* off_si2 = off_si + NMN + 1;     // NM+1

  int* bsum = (int*)alloc(sizeof(int) * 6 * 128);

  int* list_sm  = (int*)alloc(sizeof(int) * ESM);
  int* list_ms  = (int*)alloc(sizeof(int) * ESM);
  int* list_rm  = (int*)alloc(sizeof(int) * ERM);
  int* list_mr  = (int*)alloc(sizeof(int) * ERM);
  int* list_si  = (int*)alloc(sizeof(int) * ESIM);
  int* list_si2 = (int*)alloc(sizeof(int) * ESIM);

  float* dinv1 = (float*)alloc(sizeof(float) * NMN);
  float* dinv2 = (float*)alloc(sizeof(float) * NMN);
  float* xm0 = (float*)alloc(sizeof(float) * (size_t)NMN * HDIM);
  float* xm1 = (float*)alloc(sizeof(float) * (size_t)NMN * HDIM);
  float* xs0 = (float*)alloc(sizeof(float) * (size_t)NSN * HDIM);
  float* xs1 = (float*)alloc(sizeof(float) * (size_t)NSN * HDIM);
  float* xr0 = (float*)alloc(sizeof(float) * (size_t)NRN * HDIM);
  float* xr1 = (float*)alloc(sizeof(float) * (size_t)NRN * HDIM);
  float* aggbuf = (float*)alloc(sizeof(float) * (size_t)NMN * HDIM);
  float* macc   = (float*)alloc(sizeof(float) * (size_t)NMN * HDIM);
  float* WrM   = (float*)alloc(sizeof(float) * 2 * 16384);
  float* biasM = (float*)alloc(sizeof(float) * 2 * 128);

  // ---- CSR build (once; graph identical for both layers) ----
  zero_int<<<(CNT_TOTAL + 255) / 256, 256, 0, stream>>>(cnt_base, CNT_TOTAL);
  hist_kernel<<<(ESM + 255) / 256, 256, 0, stream>>>(dst_sm, ESM, cnt_sm_d);
  hist_kernel<<<(ESM + 255) / 256, 256, 0, stream>>>(src_sm, ESM, cnt_sm_s);
  hist_kernel<<<(ERM + 255) / 256, 256, 0, stream>>>(dst_rm, ERM, cnt_rm_d);
  hist_kernel<<<(ERM + 255) / 256, 256, 0, stream>>>(src_rm, ERM, cnt_rm_s);
  hist_kernel<<<(ESIM + 255) / 256, 256, 0, stream>>>(dst_sim, ESIM, cnt_si_d);
  hist_kernel<<<(ESIM + 255) / 256, 256, 0, stream>>>(src_sim, ESIM, cnt_si_s);

  auto run_scan = [&](int* cnt, int* off, int n, int* bs) {
    int nb = (n + 1023) / 1024;
    scan_partial<<<nb, 256, 0, stream>>>(cnt, n, bs);
    scan_bsum<<<1, 128, 0, stream>>>(bs, nb, off + n);
    scan_write<<<nb, 256, 0, stream>>>(cnt, n, bs, off);
  };
  run_scan(cnt_sm_d, off_sm, NMN, bsum + 0 * 128);
  run_scan(cnt_sm_s, off_ms, NSN, bsum + 1 * 128);
  run_scan(cnt_rm_d, off_rm, NMN, bsum + 2 * 128);
  run_scan(cnt_rm_s, off_mr, NRN, bsum + 3 * 128);
  run_scan(cnt_si_d, off_si, NMN, bsum + 4 * 128);
  run_scan(cnt_si_s, off_si2, NMN, bsum + 5 * 128);

  zero_int<<<(CNT_TOTAL + 255) / 256, 256, 0, stream>>>(cnt_base, CNT_TOTAL);  // reuse as cursors
  fillcsr<<<(ESM + 255) / 256, 256, 0, stream>>>(src_sm, dst_sm, ESM, off_sm, cnt_sm_d, list_sm);
  fillcsr<<<(ESM + 255) / 256, 256, 0, stream>>>(dst_sm, src_sm, ESM, off_ms, cnt_sm_s, list_ms);
  fillcsr<<<(ERM + 255) / 256, 256, 0, stream>>>(src_rm, dst_rm, ERM, off_rm, cnt_rm_d, list_rm);
  fillcsr<<<(ERM + 255) / 256, 256, 0, stream>>>(dst_rm, src_rm, ERM, off_mr, cnt_rm_s, list_mr);
  fillcsr<<<(ESIM + 255) / 256, 256, 0, stream>>>(src_sim, dst_sim, ESIM, off_si, cnt_si_d, list_si);
  fillcsr<<<(ESIM + 255) / 256, 256, 0, stream>>>(dst_sim, src_sim, ESIM, off_si2, cnt_si_s, list_si2);

  compute_dinv<<<(NMN + 255) / 256, 256, 0, stream>>>(off_si, off_si2, dinv1, dinv2, NMN);
  prep_weights<<<(2 * 16384 + 255) / 256, 256, 0, stream>>>(sWr, sbl, gb, WrM, biasM);

  // ---- layers ----
  const int AGG_B = 256;  // 4 waves/block, 1 node/wave
  for (int l = 0; l < 2; ++l) {
    const float* xs_c = l ? xs0 : emb_s;
    const float* xm_c = l ? xm0 : emb_m;
    const float* xr_c = l ? xr0 : emb_r;
    float* xs_n = l ? xs1 : xs0;
    float* xm_n = l ? xm1 : xm0;
    float* xr_n = l ? xr1 : xr0;

    const float* Wl0 = sWl + (size_t)(l * 4 + 0) * 16384;
    const float* Wl1 = sWl + (size_t)(l * 4 + 1) * 16384;
    const float* Wl2 = sWl + (size_t)(l * 4 + 2) * 16384;
    const float* Wl3 = sWl + (size_t)(l * 4 + 3) * 16384;
    const float* Wg0 = gW + (size_t)(l * 2 + 0) * 16384;
    const float* Wg1 = gW + (size_t)(l * 2 + 1) * 16384;

    // m_new = mean_sm@Wl0 + mean_rm@Wl2 + t_sim@Wg0 + t_rev@Wg1 + x_m@(Wr0+Wr2) + biasM
    sage_agg<<<(NMN + 3) / 4, AGG_B, 0, stream>>>(xs_c, list_sm, off_sm, aggbuf, NMN);
    gemm128<<<(NMN + 63) / 64, 256, 0, stream>>>(aggbuf, Wl0, nullptr, nullptr, nullptr,
                                                 biasM + l * 128, macc, NMN, 0);
    sage_agg<<<(NMN + 3) / 4, AGG_B, 0, stream>>>(xr_c, list_rm, off_rm, aggbuf, NMN);
    gemm128<<<(NMN + 63) / 64, 256, 0, stream>>>(aggbuf, Wl2, nullptr, nullptr, macc,
                                                 nullptr, macc, NMN, 0);
    gcn_agg<<<(NMN + 3) / 4, AGG_B, 0, stream>>>(xm_c, list_si, off_si, dinv1, aggbuf, NMN);
    gemm128<<<(NMN + 63) / 64, 256, 0, stream>>>(aggbuf, Wg0, nullptr, nullptr, macc,
                                                 nullptr, macc, NMN, 0);
    gcn_agg<<<(NMN + 3) / 4, AGG_B, 0, stream>>>(xm_c, list_si2, off_si2, dinv2, aggbuf, NMN);
    gemm128<<<(NMN + 63) / 64, 256, 0, stream>>>(aggbuf, Wg1, xm_c, WrM + (size_t)l * 16384,
                                                 macc, nullptr, xm_n, NMN, 1);

    // s_new = relu(mean_ms@Wl1 + x_s@Wr1 + bl1)
    sage_agg<<<(NSN + 3) / 4, AGG_B, 0, stream>>>(xm_c, list_ms, off_ms, aggbuf, NSN);
    gemm128<<<(NSN + 63) / 64, 256, 0, stream>>>(aggbuf, Wl1, xs_c, sWr + (size_t)(l * 4 + 1) * 16384,
                                                 nullptr, sbl + (l * 4 + 1) * 128, xs_n, NSN, 1);
    // r_new = relu(mean_mr@Wl3 + x_r@Wr3 + bl3)
    sage_agg<<<(NRN + 3) / 4, AGG_B, 0, stream>>>(xm_c, list_mr, off_mr, aggbuf, NRN);
    gemm128<<<(NRN + 63) / 64, 256, 0, stream>>>(aggbuf, Wl3, xr_c, sWr + (size_t)(l * 4 + 3) * 16384,
                                                 nullptr, sbl + (l * 4 + 3) * 128, xr_n, NRN, 1);
  }

  // ---- predictions ----
  dots_kernel<<<(LBL + 3) / 4, 256, 0, stream>>>(xs1, xm1, xr1, lbl_s, lbl_m, lbl_r, out);
}

// Round 2
// 2925.400 us; speedup vs baseline: 1.2692x; 1.2692x over previous
//
#include <hip/hip_runtime.h>
#include <hip/hip_bf16.h>

#define NSN 5000
#define NMN 100000
#define NRN 2000
#define HDIM 128
#define ESM 2000000
#define ERM 1000000
#define ESIM 2000000
#define LBL 500000

typedef short bf16x8 __attribute__((ext_vector_type(8)));
typedef float f32x4 __attribute__((ext_vector_type(4)));

__device__ __forceinline__ unsigned short f2bf(float f) {
  unsigned u = __float_as_uint(f);
  unsigned r = (u + 0x7fffu + ((u >> 16) & 1u)) >> 16;  // RNE
  return (unsigned short)r;
}
__device__ __forceinline__ float bf_lo(unsigned v) { return __uint_as_float(v << 16); }
__device__ __forceinline__ float bf_hi(unsigned v) { return __uint_as_float(v & 0xffff0000u); }
__device__ __forceinline__ unsigned pack2(float x, float y) {
  return (unsigned)f2bf(x) | ((unsigned)f2bf(y) << 16);
}

// ---------------- utility kernels ----------------

__global__ void zero_int(int* __restrict__ p, int n) {
  int i = blockIdx.x * blockDim.x + threadIdx.x;
  if (i < n) p[i] = 0;
}

__global__ void hist_kernel(const int* __restrict__ idx, int n, int* __restrict__ cnt) {
  int i = blockIdx.x * blockDim.x + threadIdx.x;
  if (i < n) atomicAdd(&cnt[idx[i]], 1);
}

__global__ void scan_partial(const int* __restrict__ cnt, int n, int* __restrict__ bsum) {
  __shared__ int sdata[256];
  int b = blockIdx.x, t = threadIdx.x;
  int base = b * 1024;
  int s = 0;
  for (int j = t; j < 1024; j += 256) { int i = base + j; if (i < n) s += cnt[i]; }
  sdata[t] = s; __syncthreads();
  for (int o = 128; o > 0; o >>= 1) { if (t < o) sdata[t] += sdata[t + o]; __syncthreads(); }
  if (t == 0) bsum[b] = sdata[0];
}

__global__ void scan_bsum(int* __restrict__ bsum, int nb, int* __restrict__ total_out) {
  __shared__ int buf[128];
  int t = threadIdx.x;
  int v = (t < nb) ? bsum[t] : 0;
  buf[t] = v; __syncthreads();
  for (int o = 1; o < 128; o <<= 1) {
    int a = (t >= o) ? buf[t - o] : 0;
    __syncthreads();
    buf[t] += a;
    __syncthreads();
  }
  if (t < nb) bsum[t] = buf[t] - v;
  if (t == 0) *total_out = buf[127];
}

__global__ void scan_write(const int* __restrict__ cnt, int n, const int* __restrict__ bsum,
                           int* __restrict__ off) {
  __shared__ int buf[256];
  int b = blockIdx.x, t = threadIdx.x;
  int base = b * 1024 + t * 4;
  int v0 = 0, v1 = 0, v2 = 0, v3 = 0;
  if (base + 0 < n) v0 = cnt[base + 0];
  if (base + 1 < n) v1 = cnt[base + 1];
  if (base + 2 < n) v2 = cnt[base + 2];
  if (base + 3 < n) v3 = cnt[base + 3];
  int s = v0 + v1 + v2 + v3;
  buf[t] = s; __syncthreads();
  for (int o = 1; o < 256; o <<= 1) {
    int a = (t >= o) ? buf[t - o] : 0;
    __syncthreads();
    buf[t] += a;
    __syncthreads();
  }
  int run = buf[t] - s + bsum[b];
  if (base + 0 < n) off[base + 0] = run; run += v0;
  if (base + 1 < n) off[base + 1] = run; run += v1;
  if (base + 2 < n) off[base + 2] = run; run += v2;
  if (base + 3 < n) off[base + 3] = run;
}

__global__ void fillcsr(const int* __restrict__ srcids, const int* __restrict__ dstids, int n,
                        const int* __restrict__ off, int* __restrict__ cur, int* __restrict__ list) {
  int i = blockIdx.x * blockDim.x + threadIdx.x;
  if (i < n) {
    int d = dstids[i];
    int p = atomicAdd(&cur[d], 1);
    list[off[d] + p] = srcids[i];
  }
}

__global__ void compute_dinv(const int* __restrict__ off1, const int* __restrict__ off2,
                             float* __restrict__ dinv1, float* __restrict__ dinv2, int n) {
  int v = blockIdx.x * blockDim.x + threadIdx.x;
  if (v < n) {
    dinv1[v] = rsqrtf((float)(off1[v + 1] - off1[v] + 1));
    dinv2[v] = rsqrtf((float)(off2[v + 1] - off2[v] + 1));
  }
}

// bf16 transposed weights wt[(l*9+slot)][n][k], slots:
// 0..3 = sage_Wl rel0..3; 4,5 = gcn_W; 6 = Wr0+Wr2; 7 = Wr1; 8 = Wr3
__global__ void trans_weights(const float* __restrict__ sWl, const float* __restrict__ sWr,
                              const float* __restrict__ gW, unsigned short* __restrict__ wt) {
  int i = blockIdx.x * blockDim.x + threadIdx.x;
  if (i >= 18 * 16384) return;
  int mat = i >> 14, l = mat / 9, slot = mat % 9;
  int idx = i & 16383, nn = idx >> 7, kk = idx & 127;
  int s_ = kk * 128 + nn;  // source [k][n] row-major
  float v;
  if (slot < 4)      v = sWl[((l * 4 + slot) << 14) + s_];
  else if (slot < 6) v = gW[((l * 2 + (slot - 4)) << 14) + s_];
  else if (slot == 6) v = sWr[((l * 4 + 0) << 14) + s_] + sWr[((l * 4 + 2) << 14) + s_];
  else if (slot == 7) v = sWr[((l * 4 + 1) << 14) + s_];
  else                v = sWr[((l * 4 + 3) << 14) + s_];
  wt[i] = f2bf(v);
}

__global__ void prep_bias(const float* __restrict__ sbl, const float* __restrict__ gb,
                          float* __restrict__ biasM) {
  int i = threadIdx.x;  // 256 threads
  int l = i >> 7, j = i & 127;
  biasM[i] = sbl[(l * 4 + 0) * 128 + j] + sbl[(l * 4 + 2) * 128 + j] +
             gb[(l * 2 + 0) * 128 + j] + gb[(l * 2 + 1) * 128 + j];
}

__global__ void cast_bf16(const float2* __restrict__ in, unsigned* __restrict__ out, int n) {
  int i = blockIdx.x * blockDim.x + threadIdx.x;
  if (i < n) { float2 v = in[i]; out[i] = pack2(v.x, v.y); }
}

// ---------------- aggregation (pull, one wave per dst node, bf16 features) ----------------

__global__ void sage_agg(const unsigned* __restrict__ x, const int* __restrict__ list,
                         const int* __restrict__ off, unsigned* __restrict__ outb, int n) {
  int w = (blockIdx.x * blockDim.x + threadIdx.x) >> 6;
  if (w >= n) return;
  int lane = threadIdx.x & 63;
  int s = off[w], e = off[w + 1];
  float ax = 0.f, ay = 0.f;
  int i = s;
  for (; i + 2 <= e; i += 2) {
    unsigned v0 = x[(size_t)list[i] * 64 + lane];
    unsigned v1 = x[(size_t)list[i + 1] * 64 + lane];
    ax += bf_lo(v0) + bf_lo(v1); ay += bf_hi(v0) + bf_hi(v1);
  }
  if (i < e) {
    unsigned v = x[(size_t)list[i] * 64 + lane];
    ax += bf_lo(v); ay += bf_hi(v);
  }
  float inv = (e > s) ? 1.0f / (float)(e - s) : 0.0f;
  outb[(size_t)w * 64 + lane] = pack2(ax * inv, ay * inv);
}

__global__ void gcn_agg(const unsigned* __restrict__ x, const int* __restrict__ list,
                        const int* __restrict__ off, const float* __restrict__ dinv,
                        unsigned* __restrict__ outb, int n) {
  int w = (blockIdx.x * blockDim.x + threadIdx.x) >> 6;
  if (w >= n) return;
  int lane = threadIdx.x & 63;
  int s = off[w], e = off[w + 1];
  float ax = 0.f, ay = 0.f;
  int i = s;
  for (; i + 2 <= e; i += 2) {
    int u0 = list[i], u1 = list[i + 1];
    float d0 = dinv[u0], d1 = dinv[u1];
    unsigned v0 = x[(size_t)u0 * 64 + lane];
    unsigned v1 = x[(size_t)u1 * 64 + lane];
    ax += bf_lo(v0) * d0 + bf_lo(v1) * d1;
    ay += bf_hi(v0) * d0 + bf_hi(v1) * d1;
  }
  if (i < e) {
    int u = list[i];
    float du = dinv[u];
    unsigned v = x[(size_t)u * 64 + lane];
    ax += bf_lo(v) * du; ay += bf_hi(v) * du;
  }
  float dw = dinv[w];
  unsigned xv = x[(size_t)w * 64 + lane];
  outb[(size_t)w * 64 + lane] =
      pack2(ax * dw + bf_lo(xv) * dw * dw, ay * dw + bf_hi(xv) * dw * dw);
}

// ---------------- MFMA GEMM: out = relu(bias + sum_p A_p @ W_p) ----------------
// A_p: [n,128] bf16 row-major; W_p: [128,128] bf16 TRANSPOSED ([n][k]).
// Block = 256 threads (4 waves), 64 rows x 128 cols. Wave w -> rows 16w..16w+15.
// Fragment layouts (gfx950, 16x16x32): A[m=lane&15][k=quad*8+j]; B[k=quad*8+j][n=lane&15];
// C/D: col=lane&15, row=quad*4+reg.

#define LDA 136  // bf16 stride, pad 8: row stride 272 B -> 2-way bank alias only (free)

__global__ __launch_bounds__(256) void gemm_mfma(
    const unsigned short* __restrict__ a0, const unsigned short* __restrict__ w0,
    const unsigned short* __restrict__ a1, const unsigned short* __restrict__ w1,
    const unsigned short* __restrict__ a2, const unsigned short* __restrict__ w2,
    const unsigned short* __restrict__ a3, const unsigned short* __restrict__ w3,
    const unsigned short* __restrict__ a4, const unsigned short* __restrict__ w4,
    const float* __restrict__ bias, unsigned short* __restrict__ out, int n) {
  __shared__ __align__(16) unsigned short As[64 * LDA];
  __shared__ __align__(16) unsigned short Ws[128 * LDA];

  int tid = threadIdx.x;
  int w = tid >> 6, lane = tid & 63;
  int q = lane >> 4, c = lane & 15;
  int r0 = blockIdx.x * 64;

  const unsigned short* Ap[5] = {a0, a1, a2, a3, a4};
  const unsigned short* Wp[5] = {w0, w1, w2, w3, w4};

  float bias_v[8];
#pragma unroll
  for (int n0 = 0; n0 < 8; n0++) bias_v[n0] = bias[n0 * 16 + c];

  f32x4 acc[8];
#pragma unroll
  for (int n0 = 0; n0 < 8; n0++) acc[n0] = (f32x4){0.f, 0.f, 0.f, 0.f};

  for (int p = 0; p < 5; p++) {
    if (!Ap[p]) continue;
    __syncthreads();  // LDS reuse across passes / epilogue
    // stage W (128x128 bf16) transposed layout [n][k]
    for (int j = tid; j < 2048; j += 256) {
      int row = j >> 4, colc = (j & 15) * 8;
      *(uint4*)&Ws[row * LDA + colc] = *(const uint4*)(Wp[p] + row * 128 + colc);
    }
    // stage A (64x128 bf16)
    for (int j = tid; j < 1024; j += 256) {
      int row = j >> 4, colc = (j & 15) * 8;
      uint4 v = make_uint4(0u, 0u, 0u, 0u);
      if (r0 + row < n) v = *(const uint4*)(Ap[p] + (size_t)(r0 + row) * 128 + colc);
      *(uint4*)&As[row * LDA + colc] = v;
    }
    __syncthreads();

    int arow = (w * 16 + c) * LDA;
#pragma unroll
    for (int k0 = 0; k0 < 128; k0 += 32) {
      bf16x8 af = *(const bf16x8*)&As[arow + k0 + q * 8];
#pragma unroll
      for (int n0 = 0; n0 < 8; n0++) {
        bf16x8 bfv = *(const bf16x8*)&Ws[(n0 * 16 + c) * LDA + k0 + q * 8];
        acc[n0] = __builtin_amdgcn_mfma_f32_16x16x32_bf16(af, bfv, acc[n0], 0, 0, 0);
      }
    }
  }

  // epilogue: bias + relu, transpose via LDS, coalesced bf16 store
  __syncthreads();
#pragma unroll
  for (int n0 = 0; n0 < 8; n0++) {
#pragma unroll
    for (int reg = 0; reg < 4; reg++) {
      float v = acc[n0][reg] + bias_v[n0];
      v = fmaxf(v, 0.f);
      As[(w * 16 + q * 4 + reg) * LDA + n0 * 16 + c] = f2bf(v);
    }
  }
  __syncthreads();
  for (int j = tid; j < 1024; j += 256) {
    int row = j >> 4, colc = (j & 15) * 8;
    if (r0 + row < n)
      *(uint4*)(out + (size_t)(r0 + row) * 128 + colc) = *(const uint4*)&As[row * LDA + colc];
  }
}

// ---------------- final dot products (one wave per label pair) ----------------

__global__ void dots_kernel(const unsigned* __restrict__ xs, const unsigned* __restrict__ xm,
                            const unsigned* __restrict__ xr, const int* __restrict__ ls,
                            const int* __restrict__ lm, const int* __restrict__ lr,
                            float* __restrict__ out) {
  int i = (blockIdx.x * blockDim.x + threadIdx.x) >> 6;
  if (i >= LBL) return;
  int lane = threadIdx.x & 63;
  unsigned mv = xm[(size_t)lm[i] * 64 + lane];
  unsigned sv = xs[(size_t)ls[i] * 64 + lane];
  unsigned rv = xr[(size_t)lr[i] * 64 + lane];
  float mx = bf_lo(mv), my = bf_hi(mv);
  float p1 = bf_lo(sv) * mx + bf_hi(sv) * my;
  float p2 = bf_lo(rv) * mx + bf_hi(rv) * my;
#pragma unroll
  for (int o = 32; o > 0; o >>= 1) {
    p1 += __shfl_down(p1, o, 64);
    p2 += __shfl_down(p2, o, 64);
  }
  if (lane == 0) { out[i] = p1; out[LBL + i] = p2; }
}

// ---------------- host launcher ----------------

extern "C" void kernel_launch(void* const* d_in, const int* in_sizes, int n_in,
                              void* d_out, int out_size, void* d_ws, size_t ws_size,
                              hipStream_t stream) {
  const float* emb_s = (const float*)d_in[0];
  const float* emb_m = (const float*)d_in[1];
  const float* emb_r = (const float*)d_in[2];
  const float* sWl = (const float*)d_in[3];
  const float* sbl = (const float*)d_in[4];
  const float* sWr = (const float*)d_in[5];
  const float* gW  = (const float*)d_in[6];
  const float* gb  = (const float*)d_in[7];
  const int* src_sm  = (const int*)d_in[8];
  const int* dst_sm  = (const int*)d_in[9];
  const int* src_rm  = (const int*)d_in[10];
  const int* dst_rm  = (const int*)d_in[11];
  const int* src_sim = (const int*)d_in[12];
  const int* dst_sim = (const int*)d_in[13];
  const int* lbl_s = (const int*)d_in[14];
  const int* lbl_m = (const int*)d_in[15];
  const int* lbl_r = (const int*)d_in[16];
  float* out = (float*)d_out;

  char* p = (char*)d_ws;
  auto alloc = [&](size_t bytes) -> char* {
    char* r = p;
    p += (bytes + 255) & ~(size_t)255;
    return r;
  };

  const int CNT_TOTAL = 4 * NMN + NSN + NRN;
  int* cnt_base = (int*)alloc(sizeof(int) * CNT_TOTAL);
  int* cnt_sm_d = cnt_base;
  int* cnt_sm_s = cnt_sm_d + NMN;
  int* cnt_rm_d = cnt_sm_s + NSN;
  int* cnt_rm_s = cnt_rm_d + NMN;
  int* cnt_si_d = cnt_rm_s + NRN;
  int* cnt_si_s = cnt_si_d + NMN;

  int* off_base = (int*)alloc(sizeof(int) * (CNT_TOTAL + 6));
  int* off_sm  = off_base;
  int* off_ms  = off_sm + NMN + 1;
  int* off_rm  = off_ms + NSN + 1;
  int* off_mr  = off_rm + NMN + 1;
  int* off_si  = off_mr + NRN + 1;
  int* off_si2 = off_si + NMN + 1;

  int* bsum = (int*)alloc(sizeof(int) * 6 * 128);

  int* list_sm  = (int*)alloc(sizeof(int) * ESM);
  int* list_ms  = (int*)alloc(sizeof(int) * ESM);
  int* list_rm  = (int*)alloc(sizeof(int) * ERM);
  int* list_mr  = (int*)alloc(sizeof(int) * ERM);
  int* list_si  = (int*)alloc(sizeof(int) * ESIM);
  int* list_si2 = (int*)alloc(sizeof(int) * ESIM);

  float* dinv1 = (float*)alloc(sizeof(float) * NMN);
  float* dinv2 = (float*)alloc(sizeof(float) * NMN);

  // bf16 feature buffers (uint = 2 packed bf16; 64 uints per row)
  unsigned* xsb = (unsigned*)alloc(sizeof(unsigned) * (size_t)NSN * 64);
  unsigned* xmb = (unsigned*)alloc(sizeof(unsigned) * (size_t)NMN * 64);
  unsigned* xrb = (unsigned*)alloc(sizeof(unsigned) * (size_t)NRN * 64);
  unsigned* xs0 = (unsigned*)alloc(sizeof(unsigned) * (size_t)NSN * 64);
  unsigned* xs1 = (unsigned*)alloc(sizeof(unsigned) * (size_t)NSN * 64);
  unsigned* xm0 = (unsigned*)alloc(sizeof(unsigned) * (size_t)NMN * 64);
  unsigned* xm1 = (unsigned*)alloc(sizeof(unsigned) * (size_t)NMN * 64);
  unsigned* xr0 = (unsigned*)alloc(sizeof(unsigned) * (size_t)NRN * 64);
  unsigned* xr1 = (unsigned*)alloc(sizeof(unsigned) * (size_t)NRN * 64);
  unsigned* aggA = (unsigned*)alloc(sizeof(unsigned) * (size_t)NMN * 64);
  unsigned* aggB = (unsigned*)alloc(sizeof(unsigned) * (size_t)NMN * 64);
  unsigned* aggC = (unsigned*)alloc(sizeof(unsigned) * (size_t)NMN * 64);
  unsigned* aggD = (unsigned*)alloc(sizeof(unsigned) * (size_t)NMN * 64);

  unsigned short* wt = (unsigned short*)alloc(sizeof(unsigned short) * 18 * 16384);
  float* biasM = (float*)alloc(sizeof(float) * 2 * 128);

  auto WT = [&](int l, int slot) -> const unsigned short* {
    return wt + (((size_t)l * 9 + slot) << 14);
  };

  // ---- CSR build (graph identical for both layers) ----
  zero_int<<<(CNT_TOTAL + 255) / 256, 256, 0, stream>>>(cnt_base, CNT_TOTAL);
  hist_kernel<<<(ESM + 255) / 256, 256, 0, stream>>>(dst_sm, ESM, cnt_sm_d);
  hist_kernel<<<(ESM + 255) / 256, 256, 0, stream>>>(src_sm, ESM, cnt_sm_s);
  hist_kernel<<<(ERM + 255) / 256, 256, 0, stream>>>(dst_rm, ERM, cnt_rm_d);
  hist_kernel<<<(ERM + 255) / 256, 256, 0, stream>>>(src_rm, ERM, cnt_rm_s);
  hist_kernel<<<(ESIM + 255) / 256, 256, 0, stream>>>(dst_sim, ESIM, cnt_si_d);
  hist_kernel<<<(ESIM + 255) / 256, 256, 0, stream>>>(src_sim, ESIM, cnt_si_s);

  auto run_scan = [&](int* cnt, int* off, int n, int* bs) {
    int nb = (n + 1023) / 1024;
    scan_partial<<<nb, 256, 0, stream>>>(cnt, n, bs);
    scan_bsum<<<1, 128, 0, stream>>>(bs, nb, off + n);
    scan_write<<<nb, 256, 0, stream>>>(cnt, n, bs, off);
  };
  run_scan(cnt_sm_d, off_sm, NMN, bsum + 0 * 128);
  run_scan(cnt_sm_s, off_ms, NSN, bsum + 1 * 128);
  run_scan(cnt_rm_d, off_rm, NMN, bsum + 2 * 128);
  run_scan(cnt_rm_s, off_mr, NRN, bsum + 3 * 128);
  run_scan(cnt_si_d, off_si, NMN, bsum + 4 * 128);
  run_scan(cnt_si_s, off_si2, NMN, bsum + 5 * 128);

  zero_int<<<(CNT_TOTAL + 255) / 256, 256, 0, stream>>>(cnt_base, CNT_TOTAL);
  fillcsr<<<(ESM + 255) / 256, 256, 0, stream>>>(src_sm, dst_sm, ESM, off_sm, cnt_sm_d, list_sm);
  fillcsr<<<(ESM + 255) / 256, 256, 0, stream>>>(dst_sm, src_sm, ESM, off_ms, cnt_sm_s, list_ms);
  fillcsr<<<(ERM + 255) / 256, 256, 0, stream>>>(src_rm, dst_rm, ERM, off_rm, cnt_rm_d, list_rm);
  fillcsr<<<(ERM + 255) / 256, 256, 0, stream>>>(dst_rm, src_rm, ERM, off_mr, cnt_rm_s, list_mr);
  fillcsr<<<(ESIM + 255) / 256, 256, 0, stream>>>(src_sim, dst_sim, ESIM, off_si, cnt_si_d, list_si);
  fillcsr<<<(ESIM + 255) / 256, 256, 0, stream>>>(dst_sim, src_sim, ESIM, off_si2, cnt_si_s, list_si2);

  compute_dinv<<<(NMN + 255) / 256, 256, 0, stream>>>(off_si, off_si2, dinv1, dinv2, NMN);
  trans_weights<<<(18 * 16384 + 255) / 256, 256, 0, stream>>>(sWl, sWr, gW, wt);
  prep_bias<<<1, 256, 0, stream>>>(sbl, gb, biasM);

  // cast embeddings to bf16
  cast_bf16<<<(NSN * 64 + 255) / 256, 256, 0, stream>>>((const float2*)emb_s, xsb, NSN * 64);
  cast_bf16<<<(NMN * 64 + 255) / 256, 256, 0, stream>>>((const float2*)emb_m, xmb, NMN * 64);
  cast_bf16<<<(NRN * 64 + 255) / 256, 256, 0, stream>>>((const float2*)emb_r, xrb, NRN * 64);

  const int AGG_B = 256;
  for (int l = 0; l < 2; ++l) {
    const unsigned* xs_c = l ? xs0 : xsb;
    const unsigned* xm_c = l ? xm0 : xmb;
    const unsigned* xr_c = l ? xr0 : xrb;
    unsigned* xs_n = l ? xs1 : xs0;
    unsigned* xm_n = l ? xm1 : xm0;
    unsigned* xr_n = l ? xr1 : xr0;

    sage_agg<<<(NMN + 3) / 4, AGG_B, 0, stream>>>(xs_c, list_sm, off_sm, aggA, NMN);
    sage_agg<<<(NMN + 3) / 4, AGG_B, 0, stream>>>(xr_c, list_rm, off_rm, aggB, NMN);
    gcn_agg<<<(NMN + 3) / 4, AGG_B, 0, stream>>>(xm_c, list_si, off_si, dinv1, aggC, NMN);
    gcn_agg<<<(NMN + 3) / 4, AGG_B, 0, stream>>>(xm_c, list_si2, off_si2, dinv2, aggD, NMN);
    // m_new = relu(biasM + aggA@Wl0 + aggB@Wl2 + aggC@Wg0 + aggD@Wg1 + x_m@WrM)
    gemm_mfma<<<(NMN + 63) / 64, 256, 0, stream>>>(
        (const unsigned short*)aggA, WT(l, 0), (const unsigned short*)aggB, WT(l, 2),
        (const unsigned short*)aggC, WT(l, 4), (const unsigned short*)aggD, WT(l, 5),
        (const unsigned short*)xm_c, WT(l, 6), biasM + l * 128,
        (unsigned short*)xm_n, NMN);

    // s_new = relu(bl1 + mean_ms@Wl1 + x_s@Wr1)
    sage_agg<<<(NSN + 3) / 4, AGG_B, 0, stream>>>(xm_c, list_ms, off_ms, aggA, NSN);
    gemm_mfma<<<(NSN + 63) / 64, 256, 0, stream>>>(
        (const unsigned short*)aggA, WT(l, 1), (const unsigned short*)xs_c, WT(l, 7),
        nullptr, nullptr, nullptr, nullptr, nullptr, nullptr,
        sbl + (l * 4 + 1) * 128, (unsigned short*)xs_n, NSN);

    // r_new = relu(bl3 + mean_mr@Wl3 + x_r@Wr3)
    sage_agg<<<(NRN + 3) / 4, AGG_B, 0, stream>>>(xm_c, list_mr, off_mr, aggB, NRN);
    gemm_mfma<<<(NRN + 63) / 64, 256, 0, stream>>>(
        (const unsigned short*)aggB, WT(l, 3), (const unsigned short*)xr_c, WT(l, 8),
        nullptr, nullptr, nullptr, nullptr, nullptr, nullptr,
        sbl + (l * 4 + 3) * 128, (unsigned short*)xr_n, NRN);
  }

  dots_kernel<<<(LBL + 3) / 4, 256, 0, stream>>>(xs1, xm1, xr1, lbl_s, lbl_m, lbl_r, out);
}

// Round 3
// 2297.656 us; speedup vs baseline: 1.6159x; 1.2732x over previous
//
#include <hip/hip_runtime.h>
#include <hip/hip_bf16.h>

#define NSN 5000
#define NMN 100000
#define NRN 2000
#define HDIM 128
#define ESM 2000000
#define ERM 1000000
#define ESIM 2000000
#define LBL 500000

#define CNT_TOTAL (4 * NMN + NSN + NRN)  // 407000
#define POOL_TOTAL (2 * ESM + 2 * ERM + 2 * ESIM)  // 10M

typedef short bf16x8 __attribute__((ext_vector_type(8)));
typedef float f32x4 __attribute__((ext_vector_type(4)));

__device__ __forceinline__ unsigned short f2bf(float f) {
  unsigned u = __float_as_uint(f);
  unsigned r = (u + 0x7fffu + ((u >> 16) & 1u)) >> 16;  // RNE
  return (unsigned short)r;
}
__device__ __forceinline__ float bf_lo(unsigned v) { return __uint_as_float(v << 16); }
__device__ __forceinline__ float bf_hi(unsigned v) { return __uint_as_float(v & 0xffff0000u); }
__device__ __forceinline__ unsigned pack2(float x, float y) {
  return (unsigned)f2bf(x) | ((unsigned)f2bf(y) << 16);
}

// ---------------- CSR build ----------------

__global__ void zero_int(int* __restrict__ p, int n) {
  int i = blockIdx.x * blockDim.x + threadIdx.x;
  if (i < n) p[i] = 0;
}

// combined forward+reverse histogram
__global__ void hist2(const int* __restrict__ a, const int* __restrict__ b, int n,
                      int* __restrict__ cntA, int* __restrict__ cntB) {
  int i = blockIdx.x * blockDim.x + threadIdx.x;
  if (i < n) {
    atomicAdd(&cntA[b[i]], 1);  // dst-indexed
    atomicAdd(&cntB[a[i]], 1);  // src-indexed
  }
}

// global 3-phase exclusive scan over the whole cnt buffer (407000 elems)
__global__ void scan_partial(const int* __restrict__ cnt, int n, int* __restrict__ bsum) {
  __shared__ int sdata[256];
  int b = blockIdx.x, t = threadIdx.x;
  int base = b * 1024;
  int s = 0;
  for (int j = t; j < 1024; j += 256) { int i = base + j; if (i < n) s += cnt[i]; }
  sdata[t] = s; __syncthreads();
  for (int o = 128; o > 0; o >>= 1) { if (t < o) sdata[t] += sdata[t + o]; __syncthreads(); }
  if (t == 0) bsum[b] = sdata[0];
}

__global__ void scan_bsum(int* __restrict__ bsum, int nb, int* __restrict__ off_end) {
  __shared__ int buf[512];
  int t = threadIdx.x;  // 512 threads
  int v = (t < nb) ? bsum[t] : 0;
  buf[t] = v; __syncthreads();
  for (int o = 1; o < 512; o <<= 1) {
    int a = (t >= o) ? buf[t - o] : 0;
    __syncthreads();
    buf[t] += a;
    __syncthreads();
  }
  if (t < nb) bsum[t] = buf[t] - v;     // exclusive
  if (t == 511) *off_end = buf[511];    // grand total -> off[CNT_TOTAL]
}

__global__ void scan_write(const int* __restrict__ cnt, int n, const int* __restrict__ bsum,
                           int* __restrict__ off) {
  __shared__ int buf[256];
  int b = blockIdx.x, t = threadIdx.x;
  int base = b * 1024 + t * 4;
  int v0 = 0, v1 = 0, v2 = 0, v3 = 0;
  if (base + 0 < n) v0 = cnt[base + 0];
  if (base + 1 < n) v1 = cnt[base + 1];
  if (base + 2 < n) v2 = cnt[base + 2];
  if (base + 3 < n) v3 = cnt[base + 3];
  int s = v0 + v1 + v2 + v3;
  buf[t] = s; __syncthreads();
  for (int o = 1; o < 256; o <<= 1) {
    int a = (t >= o) ? buf[t - o] : 0;
    __syncthreads();
    buf[t] += a;
    __syncthreads();
  }
  int run = buf[t] - s + bsum[b];
  if (base + 0 < n) off[base + 0] = run; run += v0;
  if (base + 1 < n) off[base + 1] = run; run += v1;
  if (base + 2 < n) off[base + 2] = run; run += v2;
  if (base + 3 < n) off[base + 3] = run;
}

// combined forward+reverse CSR fill; offsets are POOL-GLOBAL, lists share `pool`
__global__ void fillcsr2(const int* __restrict__ a, const int* __restrict__ b, int n,
                         const int* __restrict__ offA, int* __restrict__ curA,
                         const int* __restrict__ offB, int* __restrict__ curB,
                         int* __restrict__ pool) {
  int i = blockIdx.x * blockDim.x + threadIdx.x;
  if (i < n) {
    int s_ = a[i], d = b[i];
    int p = atomicAdd(&curA[d], 1);
    pool[offA[d] + p] = s_;
    int q = atomicAdd(&curB[s_], 1);
    pool[offB[s_] + q] = d;
  }
}

__global__ void compute_dinv(const int* __restrict__ off1, const int* __restrict__ off2,
                             float* __restrict__ dinv1, float* __restrict__ dinv2, int n) {
  int v = blockIdx.x * blockDim.x + threadIdx.x;
  if (v < n) {
    dinv1[v] = rsqrtf((float)(off1[v + 1] - off1[v] + 1));
    dinv2[v] = rsqrtf((float)(off2[v + 1] - off2[v] + 1));
  }
}

// bf16 transposed weights wt[(l*9+slot)][n][k], slots:
// 0..3 = sage_Wl rel0..3; 4,5 = gcn_W; 6 = Wr0+Wr2; 7 = Wr1; 8 = Wr3
__global__ void trans_weights(const float* __restrict__ sWl, const float* __restrict__ sWr,
                              const float* __restrict__ gW, unsigned short* __restrict__ wt) {
  int i = blockIdx.x * blockDim.x + threadIdx.x;
  if (i >= 18 * 16384) return;
  int mat = i >> 14, l = mat / 9, slot = mat % 9;
  int idx = i & 16383, nn = idx >> 7, kk = idx & 127;
  int s_ = kk * 128 + nn;  // source [k][n] row-major
  float v;
  if (slot < 4)      v = sWl[((l * 4 + slot) << 14) + s_];
  else if (slot < 6) v = gW[((l * 2 + (slot - 4)) << 14) + s_];
  else if (slot == 6) v = sWr[((l * 4 + 0) << 14) + s_] + sWr[((l * 4 + 2) << 14) + s_];
  else if (slot == 7) v = sWr[((l * 4 + 1) << 14) + s_];
  else                v = sWr[((l * 4 + 3) << 14) + s_];
  wt[i] = f2bf(v);
}

__global__ void prep_bias(const float* __restrict__ sbl, const float* __restrict__ gb,
                          float* __restrict__ biasM) {
  int i = threadIdx.x;  // 256 threads
  int l = i >> 7, j = i & 127;
  biasM[i] = sbl[(l * 4 + 0) * 128 + j] + sbl[(l * 4 + 2) * 128 + j] +
             gb[(l * 2 + 0) * 128 + j] + gb[(l * 2 + 1) * 128 + j];
}

// one merged cast for all three embedding tables
__global__ void cast_all(const float2* __restrict__ es, const float2* __restrict__ em,
                         const float2* __restrict__ er, unsigned* __restrict__ os,
                         unsigned* __restrict__ om, unsigned* __restrict__ orr) {
  int i = blockIdx.x * blockDim.x + threadIdx.x;
  if (i < NSN * 64) {
    float2 v = es[i]; os[i] = pack2(v.x, v.y);
  }
  if (i < NMN * 64) {
    float2 v = em[i]; om[i] = pack2(v.x, v.y);
  }
  if (i < NRN * 64) {
    float2 v = er[i]; orr[i] = pack2(v.x, v.y);
  }
}

// ---------------- aggregation ----------------
// 1 wave per dst node (NM targets, low degree), unroll-4 ILP

__global__ void sage_agg(const unsigned* __restrict__ x, const int* __restrict__ pool,
                         const int* __restrict__ off, unsigned* __restrict__ outb, int n) {
  int w = (blockIdx.x * blockDim.x + threadIdx.x) >> 6;
  if (w >= n) return;
  int lane = threadIdx.x & 63;
  int s = off[w], e = off[w + 1];
  float ax = 0.f, ay = 0.f;
  int i = s;
  for (; i + 3 < e; i += 4) {
    int u0 = pool[i], u1 = pool[i + 1], u2 = pool[i + 2], u3 = pool[i + 3];
    unsigned v0 = x[(size_t)u0 * 64 + lane];
    unsigned v1 = x[(size_t)u1 * 64 + lane];
    unsigned v2 = x[(size_t)u2 * 64 + lane];
    unsigned v3 = x[(size_t)u3 * 64 + lane];
    ax += (bf_lo(v0) + bf_lo(v1)) + (bf_lo(v2) + bf_lo(v3));
    ay += (bf_hi(v0) + bf_hi(v1)) + (bf_hi(v2) + bf_hi(v3));
  }
  for (; i < e; ++i) {
    unsigned v = x[(size_t)pool[i] * 64 + lane];
    ax += bf_lo(v); ay += bf_hi(v);
  }
  float inv = (e > s) ? 1.0f / (float)(e - s) : 0.0f;
  outb[(size_t)w * 64 + lane] = pack2(ax * inv, ay * inv);
}

// 4 waves per dst node (NS/NR targets, high degree), LDS combine
__global__ __launch_bounds__(256) void sage_agg_mw(const unsigned* __restrict__ x,
                                                   const int* __restrict__ pool,
                                                   const int* __restrict__ off,
                                                   unsigned* __restrict__ outb, int n) {
  __shared__ float2 psum[3][64];
  int node = blockIdx.x;
  if (node >= n) return;
  int sub = threadIdx.x >> 6, lane = threadIdx.x & 63;
  int s = off[node], e = off[node + 1];
  float ax = 0.f, ay = 0.f;
  int i = s + sub;
  for (; i + 12 < e; i += 16) {
    int u0 = pool[i], u1 = pool[i + 4], u2 = pool[i + 8], u3 = pool[i + 12];
    unsigned v0 = x[(size_t)u0 * 64 + lane];
    unsigned v1 = x[(size_t)u1 * 64 + lane];
    unsigned v2 = x[(size_t)u2 * 64 + lane];
    unsigned v3 = x[(size_t)u3 * 64 + lane];
    ax += (bf_lo(v0) + bf_lo(v1)) + (bf_lo(v2) + bf_lo(v3));
    ay += (bf_hi(v0) + bf_hi(v1)) + (bf_hi(v2) + bf_hi(v3));
  }
  for (; i < e; i += 4) {
    unsigned v = x[(size_t)pool[i] * 64 + lane];
    ax += bf_lo(v); ay += bf_hi(v);
  }
  if (sub) psum[sub - 1][lane] = make_float2(ax, ay);
  __syncthreads();
  if (sub == 0) {
#pragma unroll
    for (int j = 0; j < 3; j++) {
      float2 t = psum[j][lane];
      ax += t.x; ay += t.y;
    }
    float inv = (e > s) ? 1.0f / (float)(e - s) : 0.0f;
    outb[(size_t)node * 64 + lane] = pack2(ax * inv, ay * inv);
  }
}

__global__ void gcn_agg(const unsigned* __restrict__ x, const int* __restrict__ pool,
                        const int* __restrict__ off, const float* __restrict__ dinv,
                        unsigned* __restrict__ outb, int n) {
  int w = (blockIdx.x * blockDim.x + threadIdx.x) >> 6;
  if (w >= n) return;
  int lane = threadIdx.x & 63;
  int s = off[w], e = off[w + 1];
  float ax = 0.f, ay = 0.f;
  int i = s;
  for (; i + 3 < e; i += 4) {
    int u0 = pool[i], u1 = pool[i + 1], u2 = pool[i + 2], u3 = pool[i + 3];
    float d0 = dinv[u0], d1 = dinv[u1], d2 = dinv[u2], d3 = dinv[u3];
    unsigned v0 = x[(size_t)u0 * 64 + lane];
    unsigned v1 = x[(size_t)u1 * 64 + lane];
    unsigned v2 = x[(size_t)u2 * 64 + lane];
    unsigned v3 = x[(size_t)u3 * 64 + lane];
    ax += bf_lo(v0) * d0 + bf_lo(v1) * d1 + bf_lo(v2) * d2 + bf_lo(v3) * d3;
    ay += bf_hi(v0) * d0 + bf_hi(v1) * d1 + bf_hi(v2) * d2 + bf_hi(v3) * d3;
  }
  for (; i < e; ++i) {
    int u = pool[i];
    float du = dinv[u];
    unsigned v = x[(size_t)u * 64 + lane];
    ax += bf_lo(v) * du; ay += bf_hi(v) * du;
  }
  float dw = dinv[w];
  unsigned xv = x[(size_t)w * 64 + lane];
  outb[(size_t)w * 64 + lane] =
      pack2(ax * dw + bf_lo(xv) * dw * dw, ay * dw + bf_hi(xv) * dw * dw);
}

// ---------------- MFMA GEMM: out = relu(bias + sum_p A_p @ W_p) ----------------

#define LDA 136

__global__ __launch_bounds__(256) void gemm_mfma(
    const unsigned short* __restrict__ a0, const unsigned short* __restrict__ w0,
    const unsigned short* __restrict__ a1, const unsigned short* __restrict__ w1,
    const unsigned short* __restrict__ a2, const unsigned short* __restrict__ w2,
    const unsigned short* __restrict__ a3, const unsigned short* __restrict__ w3,
    const unsigned short* __restrict__ a4, const unsigned short* __restrict__ w4,
    const float* __restrict__ bias, unsigned short* __restrict__ out, int n) {
  __shared__ __align__(16) unsigned short As[64 * LDA];
  __shared__ __align__(16) unsigned short Ws[128 * LDA];

  int tid = threadIdx.x;
  int w = tid >> 6, lane = tid & 63;
  int q = lane >> 4, c = lane & 15;
  int r0 = blockIdx.x * 64;

  const unsigned short* Ap[5] = {a0, a1, a2, a3, a4};
  const unsigned short* Wp[5] = {w0, w1, w2, w3, w4};

  float bias_v[8];
#pragma unroll
  for (int n0 = 0; n0 < 8; n0++) bias_v[n0] = bias[n0 * 16 + c];

  f32x4 acc[8];
#pragma unroll
  for (int n0 = 0; n0 < 8; n0++) acc[n0] = (f32x4){0.f, 0.f, 0.f, 0.f};

  for (int p = 0; p < 5; p++) {
    if (!Ap[p]) continue;
    __syncthreads();
    for (int j = tid; j < 2048; j += 256) {
      int row = j >> 4, colc = (j & 15) * 8;
      *(uint4*)&Ws[row * LDA + colc] = *(const uint4*)(Wp[p] + row * 128 + colc);
    }
    for (int j = tid; j < 1024; j += 256) {
      int row = j >> 4, colc = (j & 15) * 8;
      uint4 v = make_uint4(0u, 0u, 0u, 0u);
      if (r0 + row < n) v = *(const uint4*)(Ap[p] + (size_t)(r0 + row) * 128 + colc);
      *(uint4*)&As[row * LDA + colc] = v;
    }
    __syncthreads();

    int arow = (w * 16 + c) * LDA;
#pragma unroll
    for (int k0 = 0; k0 < 128; k0 += 32) {
      bf16x8 af = *(const bf16x8*)&As[arow + k0 + q * 8];
#pragma unroll
      for (int n0 = 0; n0 < 8; n0++) {
        bf16x8 bfv = *(const bf16x8*)&Ws[(n0 * 16 + c) * LDA + k0 + q * 8];
        acc[n0] = __builtin_amdgcn_mfma_f32_16x16x32_bf16(af, bfv, acc[n0], 0, 0, 0);
      }
    }
  }

  __syncthreads();
#pragma unroll
  for (int n0 = 0; n0 < 8; n0++) {
#pragma unroll
    for (int reg = 0; reg < 4; reg++) {
      float v = acc[n0][reg] + bias_v[n0];
      v = fmaxf(v, 0.f);
      As[(w * 16 + q * 4 + reg) * LDA + n0 * 16 + c] = f2bf(v);
    }
  }
  __syncthreads();
  for (int j = tid; j < 1024; j += 256) {
    int row = j >> 4, colc = (j & 15) * 8;
    if (r0 + row < n)
      *(uint4*)(out + (size_t)(r0 + row) * 128 + colc) = *(const uint4*)&As[row * LDA + colc];
  }
}

// ---------------- final dot products ----------------

__global__ void dots_kernel(const unsigned* __restrict__ xs, const unsigned* __restrict__ xm,
                            const unsigned* __restrict__ xr, const int* __restrict__ ls,
                            const int* __restrict__ lm, const int* __restrict__ lr,
                            float* __restrict__ out) {
  int i = (blockIdx.x * blockDim.x + threadIdx.x) >> 6;
  if (i >= LBL) return;
  int lane = threadIdx.x & 63;
  unsigned mv = xm[(size_t)lm[i] * 64 + lane];
  unsigned sv = xs[(size_t)ls[i] * 64 + lane];
  unsigned rv = xr[(size_t)lr[i] * 64 + lane];
  float mx = bf_lo(mv), my = bf_hi(mv);
  float p1 = bf_lo(sv) * mx + bf_hi(sv) * my;
  float p2 = bf_lo(rv) * mx + bf_hi(rv) * my;
#pragma unroll
  for (int o = 32; o > 0; o >>= 1) {
    p1 += __shfl_down(p1, o, 64);
    p2 += __shfl_down(p2, o, 64);
  }
  if (lane == 0) { out[i] = p1; out[LBL + i] = p2; }
}

// ---------------- host launcher ----------------

extern "C" void kernel_launch(void* const* d_in, const int* in_sizes, int n_in,
                              void* d_out, int out_size, void* d_ws, size_t ws_size,
                              hipStream_t stream) {
  const float* emb_s = (const float*)d_in[0];
  const float* emb_m = (const float*)d_in[1];
  const float* emb_r = (const float*)d_in[2];
  const float* sWl = (const float*)d_in[3];
  const float* sbl = (const float*)d_in[4];
  const float* sWr = (const float*)d_in[5];
  const float* gW  = (const float*)d_in[6];
  const float* gb  = (const float*)d_in[7];
  const int* src_sm  = (const int*)d_in[8];
  const int* dst_sm  = (const int*)d_in[9];
  const int* src_rm  = (const int*)d_in[10];
  const int* dst_rm  = (const int*)d_in[11];
  const int* src_sim = (const int*)d_in[12];
  const int* dst_sim = (const int*)d_in[13];
  const int* lbl_s = (const int*)d_in[14];
  const int* lbl_m = (const int*)d_in[15];
  const int* lbl_r = (const int*)d_in[16];
  float* out = (float*)d_out;

  char* p = (char*)d_ws;
  auto alloc = [&](size_t bytes) -> char* {
    char* r = p;
    p += (bytes + 255) & ~(size_t)255;
    return r;
  };

  // cnt groups in pool order: sm_d(NM), sm_s(NS), rm_d(NM), rm_s(NR), si_d(NM), si_s(NM)
  int* cnt_base = (int*)alloc(sizeof(int) * CNT_TOTAL);
  int* cnt_sm_d = cnt_base;
  int* cnt_sm_s = cnt_sm_d + NMN;
  int* cnt_rm_d = cnt_sm_s + NSN;
  int* cnt_rm_s = cnt_rm_d + NMN;
  int* cnt_si_d = cnt_rm_s + NRN;
  int* cnt_si_s = cnt_si_d + NMN;

  int* off_base = (int*)alloc(sizeof(int) * (CNT_TOTAL + 1));
  int* off_sm  = off_base;              // NM+1 (end = start of next group)
  int* off_ms  = off_sm + NMN;          // NS+1
  int* off_rm  = off_ms + NSN;          // NM+1
  int* off_mr  = off_rm + NMN;          // NR+1
  int* off_si  = off_mr + NRN;          // NM+1
  int* off_si2 = off_si + NMN;          // NM+1 (last entry = POOL_TOTAL)

  int* bsum = (int*)alloc(sizeof(int) * 512);
  int* pool = (int*)alloc(sizeof(int) * POOL_TOTAL);  // all 6 adjacency lists

  float* dinv1 = (float*)alloc(sizeof(float) * NMN);
  float* dinv2 = (float*)alloc(sizeof(float) * NMN);

  unsigned* xsb = (unsigned*)alloc(sizeof(unsigned) * (size_t)NSN * 64);
  unsigned* xmb = (unsigned*)alloc(sizeof(unsigned) * (size_t)NMN * 64);
  unsigned* xrb = (unsigned*)alloc(sizeof(unsigned) * (size_t)NRN * 64);
  unsigned* xs0 = (unsigned*)alloc(sizeof(unsigned) * (size_t)NSN * 64);
  unsigned* xs1 = (unsigned*)alloc(sizeof(unsigned) * (size_t)NSN * 64);
  unsigned* xm0 = (unsigned*)alloc(sizeof(unsigned) * (size_t)NMN * 64);
  unsigned* xm1 = (unsigned*)alloc(sizeof(unsigned) * (size_t)NMN * 64);
  unsigned* xr0 = (unsigned*)alloc(sizeof(unsigned) * (size_t)NRN * 64);
  unsigned* xr1 = (unsigned*)alloc(sizeof(unsigned) * (size_t)NRN * 64);
  unsigned* aggA = (unsigned*)alloc(sizeof(unsigned) * (size_t)NMN * 64);
  unsigned* aggB = (unsigned*)alloc(sizeof(unsigned) * (size_t)NMN * 64);
  unsigned* aggC = (unsigned*)alloc(sizeof(unsigned) * (size_t)NMN * 64);
  unsigned* aggD = (unsigned*)alloc(sizeof(unsigned) * (size_t)NMN * 64);

  unsigned short* wt = (unsigned short*)alloc(sizeof(unsigned short) * 18 * 16384);
  float* biasM = (float*)alloc(sizeof(float) * 2 * 128);

  auto WT = [&](int l, int slot) -> const unsigned short* {
    return wt + (((size_t)l * 9 + slot) << 14);
  };

  // ---- CSR build ----
  zero_int<<<(CNT_TOTAL + 255) / 256, 256, 0, stream>>>(cnt_base, CNT_TOTAL);
  hist2<<<(ESM + 255) / 256, 256, 0, stream>>>(src_sm, dst_sm, ESM, cnt_sm_d, cnt_sm_s);
  hist2<<<(ERM + 255) / 256, 256, 0, stream>>>(src_rm, dst_rm, ERM, cnt_rm_d, cnt_rm_s);
  hist2<<<(ESIM + 255) / 256, 256, 0, stream>>>(src_sim, dst_sim, ESIM, cnt_si_d, cnt_si_s);

  const int NB = (CNT_TOTAL + 1023) / 1024;  // 398
  scan_partial<<<NB, 256, 0, stream>>>(cnt_base, CNT_TOTAL, bsum);
  scan_bsum<<<1, 512, 0, stream>>>(bsum, NB, off_base + CNT_TOTAL);
  scan_write<<<NB, 256, 0, stream>>>(cnt_base, CNT_TOTAL, bsum, off_base);

  zero_int<<<(CNT_TOTAL + 255) / 256, 256, 0, stream>>>(cnt_base, CNT_TOTAL);  // cursors
  fillcsr2<<<(ESM + 255) / 256, 256, 0, stream>>>(src_sm, dst_sm, ESM,
                                                  off_sm, cnt_sm_d, off_ms, cnt_sm_s, pool);
  fillcsr2<<<(ERM + 255) / 256, 256, 0, stream>>>(src_rm, dst_rm, ERM,
                                                  off_rm, cnt_rm_d, off_mr, cnt_rm_s, pool);
  fillcsr2<<<(ESIM + 255) / 256, 256, 0, stream>>>(src_sim, dst_sim, ESIM,
                                                   off_si, cnt_si_d, off_si2, cnt_si_s, pool);

  compute_dinv<<<(NMN + 255) / 256, 256, 0, stream>>>(off_si, off_si2, dinv1, dinv2, NMN);
  trans_weights<<<(18 * 16384 + 255) / 256, 256, 0, stream>>>(sWl, sWr, gW, wt);
  prep_bias<<<1, 256, 0, stream>>>(sbl, gb, biasM);
  cast_all<<<(NMN * 64 + 255) / 256, 256, 0, stream>>>((const float2*)emb_s, (const float2*)emb_m,
                                                       (const float2*)emb_r, xsb, xmb, xrb);

  for (int l = 0; l < 2; ++l) {
    const unsigned* xs_c = l ? xs0 : xsb;
    const unsigned* xm_c = l ? xm0 : xmb;
    const unsigned* xr_c = l ? xr0 : xrb;
    unsigned* xs_n = l ? xs1 : xs0;
    unsigned* xm_n = l ? xm1 : xm0;
    unsigned* xr_n = l ? xr1 : xr0;

    sage_agg<<<(NMN + 3) / 4, 256, 0, stream>>>(xs_c, pool, off_sm, aggA, NMN);
    sage_agg<<<(NMN + 3) / 4, 256, 0, stream>>>(xr_c, pool, off_rm, aggB, NMN);
    gcn_agg<<<(NMN + 3) / 4, 256, 0, stream>>>(xm_c, pool, off_si, dinv1, aggC, NMN);
    gcn_agg<<<(NMN + 3) / 4, 256, 0, stream>>>(xm_c, pool, off_si2, dinv2, aggD, NMN);
    gemm_mfma<<<(NMN + 63) / 64, 256, 0, stream>>>(
        (const unsigned short*)aggA, WT(l, 0), (const unsigned short*)aggB, WT(l, 2),
        (const unsigned short*)aggC, WT(l, 4), (const unsigned short*)aggD, WT(l, 5),
        (const unsigned short*)xm_c, WT(l, 6), biasM + l * 128,
        (unsigned short*)xm_n, NMN);

    sage_agg_mw<<<NSN, 256, 0, stream>>>(xm_c, pool, off_ms, aggA, NSN);
    gemm_mfma<<<(NSN + 63) / 64, 256, 0, stream>>>(
        (const unsigned short*)aggA, WT(l, 1), (const unsigned short*)xs_c, WT(l, 7),
        nullptr, nullptr, nullptr, nullptr, nullptr, nullptr,
        sbl + (l * 4 + 1) * 128, (unsigned short*)xs_n, NSN);

    sage_agg_mw<<<NRN, 256, 0, stream>>>(xm_c, pool, off_mr, aggB, NRN);
    gemm_mfma<<<(NRN + 63) / 64, 256, 0, stream>>>(
        (const unsigned short*)aggB, WT(l, 3), (const unsigned short*)xr_c, WT(l, 8),
        nullptr, nullptr, nullptr, nullptr, nullptr, nullptr,
        sbl + (l * 4 + 3) * 128, (unsigned short*)xr_n, NRN);
  }

  dots_kernel<<<(LBL + 3) / 4, 256, 0, stream>>>(xs1, xm1, xr1, lbl_s, lbl_m, lbl_r, out);
}